// Round 22
// baseline (38.792 us; speedup 1.0000x reference)
//
#include <hip/hip_runtime.h>

// Reduced exact quadrature grid (validated R18/R19: absmax identical to the
// reference 32x63 grid): integrands bandlimited => GL-7 x uniform-13 exact.
#define NB 7
#define NA 13
#define G_REAL 91
#define NGB 3     // ceil(91/32)
#define HSTR 40   // hb row stride in f16 (80B): fragment-contiguous
#define CSTR 33   // cob row stride (f32)

typedef _Float16 f16;
typedef __attribute__((ext_vector_type(2))) _Float16 v2h;
typedef __attribute__((ext_vector_type(4))) _Float16 v4h;
typedef __attribute__((ext_vector_type(8))) _Float16 v8h;
typedef __attribute__((ext_vector_type(4))) float v4f;

__device__ __forceinline__ v2h pkrtz(float a, float b) {
    return __builtin_bit_cast(v2h, __builtin_amdgcn_cvt_pkrtz(a, b));
}

__device__ __forceinline__ void gl7(int i, float& x, float& w) {
    const float X[NB] = {-0.9491079123427585f, -0.7415311855993945f, -0.4058451513773972f,
                         0.0f, 0.4058451513773972f, 0.7415311855993945f, 0.9491079123427585f};
    const float W[NB] = {0.1294849661688697f, 0.2797053914892766f, 0.3818300505051189f,
                         0.4179591836734694f, 0.3818300505051189f, 0.2797053914892766f,
                         0.1294849661688697f};
    x = X[i]; w = W[i];
}

// real orthonormal SH (same recurrence as the reference), k in [0,25)
__device__ float realY(int k, float x, float s, float alpha) {
    const int l = (k >= 16) ? 4 : (k >= 9) ? 3 : (k >= 4) ? 2 : (k >= 1) ? 1 : 0;
    const int m = k - l * l - l;
    const int am = (m < 0) ? -m : m;
    float pmm = 0.28209479177387814f;            // sqrt(1/4pi)
    for (int mm = 1; mm <= am; ++mm)
        pmm = -sqrtf((2.0f * mm + 1.0f) / (2.0f * mm)) * s * pmm;
    float p = pmm;
    if (l > am) {
        float pm2 = pmm;
        float pm1 = sqrtf(2.0f * am + 3.0f) * x * pmm;   // P_{am+1,am}
        p = pm1;
        for (int ll = am + 2; ll <= l; ++ll) {
            const float fl = (float)ll;
            const float a = sqrtf((4.0f * fl * fl - 1.0f) / (fl * fl - am * am));
            const float b = sqrtf(((2.0f * fl + 1.0f) * ((fl - 1.0f) * (fl - 1.0f) - am * am))
                                  / ((2.0f * fl - 3.0f) * (fl * fl - am * am)));
            const float pn = a * x * pm1 - b * pm2;
            pm2 = pm1; pm1 = pn; p = pn;
        }
    }
    if (m == 0) return p;
    const float r = 1.4142135623730951f * p;
    return (m > 0) ? r * cosf(m * alpha) : r * sinf(am * alpha);
}

__device__ __forceinline__ float Yat(int k, int g, bool weighted) {
    if (k >= 25 || g >= G_REAL) return 0.0f;
    const int i = g / NA, j = g - i * NA;
    float x, w;
    gl7(i, x, w);
    const float s = sqrtf(fmaxf(1.0f - x * x, 0.0f));
    const float alpha = (6.283185307179586f / NA) * j;
    const float y = realY(k, x, s, alpha);
    return weighted ? y * (w * (6.283185307179586f / NA)) : y;
}

// ---------------------------------------------------------------------------
// Prep: one thread per table element (R19; ~2-3us).
// ---------------------------------------------------------------------------
__global__ void vg_prep(f16* __restrict__ A1buf, f16* __restrict__ B2buf) {
    const int idx0 = blockIdx.x * 256 + threadIdx.x;
    const bool isB = idx0 >= 3072;
    const int idx = isB ? idx0 - 3072 : idx0;
    const int j = idx & 7;
    const int lane = (idx >> 3) & 63;
    const int u = (idx >> 9) & 1;
    const int gb = idx >> 10;
    const int lhi = lane >> 4, llo = lane & 15;
    if (!isB) {
        const int k = (j < 4) ? (lhi * 4 + j) : (16 + lhi * 4 + (j - 4));
        const int g = gb * 32 + u * 16 + llo;
        A1buf[idx] = (f16)Yat(k, g, false);
    } else {
        const int k = u * 16 + llo;
        const int g = gb * 32 + ((j < 4) ? (lhi * 4 + j) : (16 + lhi * 4 + (j - 4)));
        B2buf[idx] = (f16)Yat(k, g, true);
    }
}

// ---------------------------------------------------------------------------
// Main fused kernel (R21 base): 256 threads per (n, parity); waves =
// (h = c-half, q = g-split).
// R22: x staged as F16 (bit-identical — the f16 cast happened at fragment
// build anyway) -> LDS 34.6KB -> 25.4KB -> 6 blocks/CU: ALL 1536 blocks
// resident in ONE batch (24 waves/CU), no dispatch tail, 6 waves/SIMD of
// barrier-latency cover. __launch_bounds__(256,6).
// ---------------------------------------------------------------------------
template <bool USE_WS>
__global__ __launch_bounds__(256, 6)
void vg_main(const float* __restrict__ x1, const float* __restrict__ x2,
             const float* __restrict__ W1s, const float* __restrict__ W2s,
             const float* __restrict__ Wouts,
             const f16* __restrict__ A1buf, const f16* __restrict__ B2buf,
             float* __restrict__ out) {
    __shared__ __align__(16) char smem[25472];
    f16* hb = (f16*)smem;                    // [2 spin][96][HSTR] f16 (phase 0)
    f16* xsl = (f16*)(smem + 15360);         // [2][2400] f16 staged x (phase 0)
    float* cob = (float*)smem;               // [96][CSTR] f32 (q=0; aliases hb)
    float* cob2 = (float*)(smem + 12672);    // [96][CSTR] f32 (q=1)

    const int bid = blockIdx.x;
    const int n = bid / 3, p = bid % 3;
    const int tid = threadIdx.x;
    const int wid = tid >> 6;
    const int h = wid & 1;       // c-half owned (main loop)
    const int q = wid >> 1;      // g-split (main loop)
    const int lane = tid & 63;
    const int lhi = lane >> 4, llo = lane & 15;

    const v4f zero4 = {0.0f, 0.0f, 0.0f, 0.0f};

    // ---- phase 0a: zero hb (padding slots must be 0) + stage x as f16
    for (int i = tid; i < 3840; i += 256) ((float*)smem)[i] = 0.0f;
    {
        const float* x1n = x1 + n * 2400;
        const float* x2n = x2 + n * 2400;
        for (int i = tid; i < 600; i += 256) {
            const float4 a = ((const float4*)x1n)[i];
            const float4 b = ((const float4*)x2n)[i];
            v4h av, bv;
            av[0] = (f16)a.x; av[1] = (f16)a.y; av[2] = (f16)a.z; av[3] = (f16)a.w;
            bv[0] = (f16)b.x; bv[1] = (f16)b.y; bv[2] = (f16)b.z; bv[3] = (f16)b.w;
            ((v4h*)xsl)[i] = av;
            ((v4h*)(xsl + 2400))[i] = bv;
        }
    }
    __syncthreads();

    // ---- phase 0b (MFMA, all 4 waves): wave (s, ct) computes its quarter.
    {
        const int s = wid & 1, ct = wid >> 1;
        const f16* xs = xsl + s * 2400;
        const float* Wp = (s ? W2s : W1s) + p * 5120;
        v8h bf[5];
#pragma unroll
        for (int l = 0; l < 5; ++l)
#pragma unroll
            for (int j = 0; j < 8; ++j) {
                const int f = (j < 4) ? (lhi * 4 + j) : (16 + lhi * 4 + (j - 4));
                bf[l][j] = (f16)Wp[l * 1024 + f * 32 + ct * 16 + llo];
            }
        f16* hbs = hb + s * 96 * HSTR;
#pragma unroll
        for (int vt = 0; vt < 5; ++vt) {
            v8h af;
            const int vkb = vt * 16 + llo;
#pragma unroll
            for (int j = 0; j < 8; ++j) {
                const int f = (j < 4) ? (lhi * 4 + j) : (16 + lhi * 4 + (j - 4));
                af[j] = (vkb < 75) ? xs[f * 75 + vkb] : (f16)0.0f;
            }
            v4f D[5];
#pragma unroll
            for (int l = 0; l < 5; ++l)
                D[l] = __builtin_amdgcn_mfma_f32_16x16x32_f16(af, bf[l], zero4, 0, 0, 0);
#pragma unroll
            for (int j = 0; j < 4; ++j) {
                const int vk = vt * 16 + lhi * 4 + j;
                if (vk < 75) {
                    const int v = (vk >= 50) ? 2 : ((vk >= 25) ? 1 : 0);
                    const int k = vk - v * 25;
                    const float val = (k < 1) ? D[0][j]
                                    : (k < 4) ? D[1][j]
                                    : (k < 9) ? D[2][j]
                                    : (k < 16) ? D[3][j]
                                    : D[4][j];
                    const int ks = (k < 16) ? ((k >> 2) * 8 + (k & 3))
                                           : (((k - 16) >> 2) * 8 + 4 + ((k - 16) & 3));
                    hbs[(v * 32 + ct * 16 + llo) * HSTR + ks] = (f16)val;
                }
            }
        }
    }
    __syncthreads();

    // ---- hoist this wave's h fragments: tiles Rn = 2*vc + h (6 x v8h = 24 VGPR)
    v8h hfr[2][3];
    {
        const f16* hfb = &hb[llo * HSTR + lhi * 8];
#pragma unroll
        for (int s = 0; s < 2; ++s)
#pragma unroll
            for (int vc = 0; vc < 3; ++vc)
                hfr[s][vc] = *(const v8h*)(hfb + (s * 96 + (2 * vc + h) * 16) * HSTR);
    }

    v4f coacc[3][2];
#pragma unroll
    for (int vc = 0; vc < 3; ++vc)
#pragma unroll
        for (int t = 0; t < 2; ++t) coacc[vc][t] = zero4;

    union A2U { v2h p[4]; v8h v; };

    auto mfma1h = [&](const v8h& a1, v4f (&ag)[2][3]) {
#pragma unroll
        for (int s = 0; s < 2; ++s)
#pragma unroll
            for (int vc = 0; vc < 3; ++vc)
                ag[s][vc] = __builtin_amdgcn_mfma_f32_16x16x32_f16(
                    a1, hfr[s][vc], zero4, 0, 0, 0);
    };

    auto crossh = [&](const v4f (&ag)[2][3], A2U (&a2u)[3], int gh) {
        v2h g1[3][2], g2[3][2];
#pragma unroll
        for (int vc = 0; vc < 3; ++vc) {
            g1[vc][0] = pkrtz(ag[0][vc][0], ag[0][vc][1]);
            g1[vc][1] = pkrtz(ag[0][vc][2], ag[0][vc][3]);
            g2[vc][0] = pkrtz(ag[1][vc][0], ag[1][vc][1]);
            g2[vc][1] = pkrtz(ag[1][vc][2], ag[1][vc][3]);
        }
#pragma unroll
        for (int jp = 0; jp < 2; ++jp) {
            a2u[0].p[gh * 2 + jp] = g1[1][jp] * g2[2][jp] - g1[2][jp] * g2[1][jp];
            a2u[1].p[gh * 2 + jp] = g1[2][jp] * g2[0][jp] - g1[0][jp] * g2[2][jp];
            a2u[2].p[gh * 2 + jp] = g1[0][jp] * g2[1][jp] - g1[1][jp] * g2[0][jp];
        }
    };

    auto mfma2 = [&](A2U (&a2u)[3], const v8h& b2lo, const v8h& b2hi) {
#pragma unroll
        for (int vc = 0; vc < 3; ++vc) {
            coacc[vc][0] = __builtin_amdgcn_mfma_f32_16x16x32_f16(a2u[vc].v, b2lo, coacc[vc][0], 0, 0, 0);
            coacc[vc][1] = __builtin_amdgcn_mfma_f32_16x16x32_f16(a2u[vc].v, b2hi, coacc[vc][1], 0, 0, 0);
        }
    };

    // ---- main loop: gb = q, q+2 (NGB = 3)
    if constexpr (USE_WS) {
        const v8h* base_a = (const v8h*)A1buf + lane;
        const v8h* base_b = (const v8h*)B2buf + lane;
        for (int gb = q; gb < NGB; gb += 2) {
            const int off = gb * 128;
            const v8h Aa = base_a[off], Ab = base_a[off + 64];
            const v8h Ba = base_b[off], Bb = base_b[off + 64];
            A2U a2u[3];
            v4f ag[2][3];
            mfma1h(Aa, ag);
            crossh(ag, a2u, 0);
            mfma1h(Ab, ag);
            crossh(ag, a2u, 1);
            mfma2(a2u, Ba, Bb);
        }
    } else {
        for (int gb = q; gb < NGB; gb += 2) {
            v8h Aa, Ab, Ba, Bb;
#pragma unroll
            for (int j = 0; j < 8; ++j) {
                const int k = (j < 4) ? (lhi * 4 + j) : (16 + lhi * 4 + (j - 4));
                Aa[j] = (f16)Yat(k, gb * 32 + llo, false);
                Ab[j] = (f16)Yat(k, gb * 32 + 16 + llo, false);
                const int gg = gb * 32 + ((j < 4) ? (lhi * 4 + j) : (16 + lhi * 4 + (j - 4)));
                Ba[j] = (f16)Yat(llo, gg, true);
                Bb[j] = (f16)Yat(16 + llo, gg, true);
            }
            A2U a2u[3];
            v4f ag[2][3];
            mfma1h(Aa, ag);
            crossh(ag, a2u, 0);
            mfma1h(Ab, ag);
            crossh(ag, a2u, 1);
            mfma2(a2u, Ba, Bb);
        }
    }

    // ---- CO: parallel write — q=0 -> cob, q=1 -> cob2 (no serialized stages).
    __syncthreads();
    {
        float* cdst = q ? cob2 : cob;
#pragma unroll
        for (int vc = 0; vc < 3; ++vc)
#pragma unroll
            for (int t = 0; t < 2; ++t)
#pragma unroll
                for (int j = 0; j < 4; ++j) {
                    const int row = (2 * vc + h) * 16 + lhi * 4 + j;
                    cdst[row * CSTR + t * 16 + llo] = coacc[vc][t][j];
                }
    }
    __syncthreads();

    // ---- epilogue (MFMA): wave v=wid<3: out = W_l^T x (cob + cob2)
    if (wid < 3) {
        const int v = wid;
        const float* Wop = Wouts + p * 5120;
        float* outp = out + (n * 96 + p * 32) * 75 + v * 25;
        const int k0s[5] = {0, 1, 4, 9, 16};
        const int kws[5] = {1, 3, 5, 7, 9};
#pragma unroll
        for (int l = 0; l < 5; ++l) {
            const int k0 = k0s[l], kw = kws[l];
            v8h Bf;
            const int kk = (llo < kw) ? (k0 + llo) : k0;
#pragma unroll
            for (int j = 0; j < 8; ++j) {
                const int a = (j < 4) ? (lhi * 4 + j) : (16 + lhi * 4 + (j - 4));
                const int ci = (v * 32 + a) * CSTR + kk;
                const float bv = (llo < kw) ? (cob[ci] + cob2[ci]) : 0.0f;
                Bf[j] = (f16)bv;
            }
#pragma unroll
            for (int bt = 0; bt < 2; ++bt) {
                v8h Af;
#pragma unroll
                for (int j = 0; j < 8; ++j) {
                    const int a = (j < 4) ? (lhi * 4 + j) : (16 + lhi * 4 + (j - 4));
                    Af[j] = (f16)Wop[l * 1024 + a * 32 + bt * 16 + llo];
                }
                v4f D = __builtin_amdgcn_mfma_f32_16x16x32_f16(Af, Bf, zero4, 0, 0, 0);
                if (llo < kw) {
#pragma unroll
                    for (int jj = 0; jj < 4; ++jj)
                        outp[(bt * 16 + lhi * 4 + jj) * 75 + k0 + llo] = D[jj];
                }
            }
        }
    }
}

extern "C" void kernel_launch(void* const* d_in, const int* in_sizes, int n_in,
                              void* d_out, int out_size, void* d_ws, size_t ws_size,
                              hipStream_t stream) {
    const float* x1 = (const float*)d_in[0];
    const float* x2 = (const float*)d_in[1];
    const float* W1s = (const float*)d_in[2];
    const float* W2s = (const float*)d_in[3];
    const float* Wouts = (const float*)d_in[4];
    float* out = (float*)d_out;

    f16* A1buf = (f16*)d_ws;                       // 3072 f16 = 6 KB
    f16* B2buf = (f16*)((char*)d_ws + 8192);       // 6 KB

    if (ws_size >= 16384) {
        vg_prep<<<24, 256, 0, stream>>>(A1buf, B2buf);
        vg_main<true><<<1536, 256, 0, stream>>>(x1, x2, W1s, W2s, Wouts,
                                                A1buf, B2buf, out);
    } else {
        vg_main<false><<<1536, 256, 0, stream>>>(x1, x2, W1s, W2s, Wouts,
                                                 nullptr, nullptr, out);
    }
}

// Round 23
// 34.123 us; speedup vs baseline: 1.1369x; 1.1369x over previous
//
#include <hip/hip_runtime.h>

// Reduced exact quadrature grid (validated R18/R19: absmax identical to the
// reference 32x63 grid): integrands bandlimited => GL-7 x uniform-13 exact.
#define NB 7
#define NA 13
#define G_REAL 91
#define NGB 3     // ceil(91/32)
#define HSTR 40   // hb row stride in f16 (80B): fragment-contiguous
#define CSTR 33   // cob row stride (f32)

typedef _Float16 f16;
typedef __attribute__((ext_vector_type(2))) _Float16 v2h;
typedef __attribute__((ext_vector_type(8))) _Float16 v8h;
typedef __attribute__((ext_vector_type(4))) float v4f;

__device__ __forceinline__ v2h pkrtz(float a, float b) {
    return __builtin_bit_cast(v2h, __builtin_amdgcn_cvt_pkrtz(a, b));
}

__device__ __forceinline__ void gl7(int i, float& x, float& w) {
    const float X[NB] = {-0.9491079123427585f, -0.7415311855993945f, -0.4058451513773972f,
                         0.0f, 0.4058451513773972f, 0.7415311855993945f, 0.9491079123427585f};
    const float W[NB] = {0.1294849661688697f, 0.2797053914892766f, 0.3818300505051189f,
                         0.4179591836734694f, 0.3818300505051189f, 0.2797053914892766f,
                         0.1294849661688697f};
    x = X[i]; w = W[i];
}

// real orthonormal SH (same recurrence as the reference), k in [0,25)
__device__ float realY(int k, float x, float s, float alpha) {
    const int l = (k >= 16) ? 4 : (k >= 9) ? 3 : (k >= 4) ? 2 : (k >= 1) ? 1 : 0;
    const int m = k - l * l - l;
    const int am = (m < 0) ? -m : m;
    float pmm = 0.28209479177387814f;            // sqrt(1/4pi)
    for (int mm = 1; mm <= am; ++mm)
        pmm = -sqrtf((2.0f * mm + 1.0f) / (2.0f * mm)) * s * pmm;
    float p = pmm;
    if (l > am) {
        float pm2 = pmm;
        float pm1 = sqrtf(2.0f * am + 3.0f) * x * pmm;   // P_{am+1,am}
        p = pm1;
        for (int ll = am + 2; ll <= l; ++ll) {
            const float fl = (float)ll;
            const float a = sqrtf((4.0f * fl * fl - 1.0f) / (fl * fl - am * am));
            const float b = sqrtf(((2.0f * fl + 1.0f) * ((fl - 1.0f) * (fl - 1.0f) - am * am))
                                  / ((2.0f * fl - 3.0f) * (fl * fl - am * am)));
            const float pn = a * x * pm1 - b * pm2;
            pm2 = pm1; pm1 = pn; p = pn;
        }
    }
    if (m == 0) return p;
    const float r = 1.4142135623730951f * p;
    return (m > 0) ? r * cosf(m * alpha) : r * sinf(am * alpha);
}

__device__ __forceinline__ float Yat(int k, int g, bool weighted) {
    if (k >= 25 || g >= G_REAL) return 0.0f;
    const int i = g / NA, j = g - i * NA;
    float x, w;
    gl7(i, x, w);
    const float s = sqrtf(fmaxf(1.0f - x * x, 0.0f));
    const float alpha = (6.283185307179586f / NA) * j;
    const float y = realY(k, x, s, alpha);
    return weighted ? y * (w * (6.283185307179586f / NA)) : y;
}

// ---------------------------------------------------------------------------
// Prep: one thread per table element (R19; ~2-3us).
// ---------------------------------------------------------------------------
__global__ void vg_prep(f16* __restrict__ A1buf, f16* __restrict__ B2buf) {
    const int idx0 = blockIdx.x * 256 + threadIdx.x;
    const bool isB = idx0 >= 3072;
    const int idx = isB ? idx0 - 3072 : idx0;
    const int j = idx & 7;
    const int lane = (idx >> 3) & 63;
    const int u = (idx >> 9) & 1;
    const int gb = idx >> 10;
    const int lhi = lane >> 4, llo = lane & 15;
    if (!isB) {
        const int k = (j < 4) ? (lhi * 4 + j) : (16 + lhi * 4 + (j - 4));
        const int g = gb * 32 + u * 16 + llo;
        A1buf[idx] = (f16)Yat(k, g, false);
    } else {
        const int k = u * 16 + llo;
        const int g = gb * 32 + ((j < 4) ? (lhi * 4 + j) : (16 + lhi * 4 + (j - 4)));
        B2buf[idx] = (f16)Yat(k, g, true);
    }
}

// ---------------------------------------------------------------------------
// Main fused kernel (R21 = session best, 34.2us): 256 threads per (n, parity);
// waves = (h = c-half, q = g-split).
// (1) x1[n]/x2[n] staged into LDS via coalesced float4 loads (f32: 16-bank
//     spread for phase-0b reads — R22's f16 staging caused 8-way conflicts);
// (2) parallel CO reduce: q=0 -> cob, q=1 -> cob2, epilogue sums.
// ---------------------------------------------------------------------------
template <bool USE_WS>
__global__ __launch_bounds__(256, 4)
void vg_main(const float* __restrict__ x1, const float* __restrict__ x2,
             const float* __restrict__ W1s, const float* __restrict__ W2s,
             const float* __restrict__ Wouts,
             const f16* __restrict__ A1buf, const f16* __restrict__ B2buf,
             float* __restrict__ out) {
    __shared__ __align__(16) char smem[34560];
    f16* hb = (f16*)smem;                    // [2 spin][96][HSTR] f16 (phase 0)
    float* xsl = (float*)(smem + 15360);     // [2][2400] f32 staged x (phase 0)
    float* cob = (float*)smem;               // [96][CSTR] f32 (q=0; aliases hb)
    float* cob2 = (float*)(smem + 15360);    // [96][CSTR] f32 (q=1; aliases xsl)

    const int bid = blockIdx.x;
    const int n = bid / 3, p = bid % 3;
    const int tid = threadIdx.x;
    const int wid = tid >> 6;
    const int h = wid & 1;       // c-half owned (main loop)
    const int q = wid >> 1;      // g-split (main loop)
    const int lane = tid & 63;
    const int lhi = lane >> 4, llo = lane & 15;

    const v4f zero4 = {0.0f, 0.0f, 0.0f, 0.0f};

    // ---- phase 0a: zero hb (padding slots must be 0) + stage x coalesced
    for (int i = tid; i < 3840; i += 256) ((float*)smem)[i] = 0.0f;
    {
        const float* x1n = x1 + n * 2400;
        const float* x2n = x2 + n * 2400;
        // 2400 floats each = 600 float4
        for (int i = tid; i < 600; i += 256) {
            ((float4*)xsl)[i] = ((const float4*)x1n)[i];
            ((float4*)(xsl + 2400))[i] = ((const float4*)x2n)[i];
        }
    }
    __syncthreads();

    // ---- phase 0b (MFMA, all 4 waves): wave (s, ct) computes its quarter.
    {
        const int s = wid & 1, ct = wid >> 1;
        const float* xs = xsl + s * 2400;
        const float* Wp = (s ? W2s : W1s) + p * 5120;
        v8h bf[5];
#pragma unroll
        for (int l = 0; l < 5; ++l)
#pragma unroll
            for (int j = 0; j < 8; ++j) {
                const int f = (j < 4) ? (lhi * 4 + j) : (16 + lhi * 4 + (j - 4));
                bf[l][j] = (f16)Wp[l * 1024 + f * 32 + ct * 16 + llo];
            }
        f16* hbs = hb + s * 96 * HSTR;
#pragma unroll
        for (int vt = 0; vt < 5; ++vt) {
            v8h af;
            const int vkb = vt * 16 + llo;
#pragma unroll
            for (int j = 0; j < 8; ++j) {
                const int f = (j < 4) ? (lhi * 4 + j) : (16 + lhi * 4 + (j - 4));
                af[j] = (vkb < 75) ? (f16)xs[f * 75 + vkb] : (f16)0.0f;
            }
            v4f D[5];
#pragma unroll
            for (int l = 0; l < 5; ++l)
                D[l] = __builtin_amdgcn_mfma_f32_16x16x32_f16(af, bf[l], zero4, 0, 0, 0);
#pragma unroll
            for (int j = 0; j < 4; ++j) {
                const int vk = vt * 16 + lhi * 4 + j;
                if (vk < 75) {
                    const int v = (vk >= 50) ? 2 : ((vk >= 25) ? 1 : 0);
                    const int k = vk - v * 25;
                    const float val = (k < 1) ? D[0][j]
                                    : (k < 4) ? D[1][j]
                                    : (k < 9) ? D[2][j]
                                    : (k < 16) ? D[3][j]
                                    : D[4][j];
                    const int ks = (k < 16) ? ((k >> 2) * 8 + (k & 3))
                                           : (((k - 16) >> 2) * 8 + 4 + ((k - 16) & 3));
                    hbs[(v * 32 + ct * 16 + llo) * HSTR + ks] = (f16)val;
                }
            }
        }
    }
    __syncthreads();

    // ---- hoist this wave's h fragments: tiles Rn = 2*vc + h (6 x v8h = 24 VGPR)
    v8h hfr[2][3];
    {
        const f16* hfb = &hb[llo * HSTR + lhi * 8];
#pragma unroll
        for (int s = 0; s < 2; ++s)
#pragma unroll
            for (int vc = 0; vc < 3; ++vc)
                hfr[s][vc] = *(const v8h*)(hfb + (s * 96 + (2 * vc + h) * 16) * HSTR);
    }

    v4f coacc[3][2];
#pragma unroll
    for (int vc = 0; vc < 3; ++vc)
#pragma unroll
        for (int t = 0; t < 2; ++t) coacc[vc][t] = zero4;

    union A2U { v2h p[4]; v8h v; };

    auto mfma1h = [&](const v8h& a1, v4f (&ag)[2][3]) {
#pragma unroll
        for (int s = 0; s < 2; ++s)
#pragma unroll
            for (int vc = 0; vc < 3; ++vc)
                ag[s][vc] = __builtin_amdgcn_mfma_f32_16x16x32_f16(
                    a1, hfr[s][vc], zero4, 0, 0, 0);
    };

    auto crossh = [&](const v4f (&ag)[2][3], A2U (&a2u)[3], int gh) {
        v2h g1[3][2], g2[3][2];
#pragma unroll
        for (int vc = 0; vc < 3; ++vc) {
            g1[vc][0] = pkrtz(ag[0][vc][0], ag[0][vc][1]);
            g1[vc][1] = pkrtz(ag[0][vc][2], ag[0][vc][3]);
            g2[vc][0] = pkrtz(ag[1][vc][0], ag[1][vc][1]);
            g2[vc][1] = pkrtz(ag[1][vc][2], ag[1][vc][3]);
        }
#pragma unroll
        for (int jp = 0; jp < 2; ++jp) {
            a2u[0].p[gh * 2 + jp] = g1[1][jp] * g2[2][jp] - g1[2][jp] * g2[1][jp];
            a2u[1].p[gh * 2 + jp] = g1[2][jp] * g2[0][jp] - g1[0][jp] * g2[2][jp];
            a2u[2].p[gh * 2 + jp] = g1[0][jp] * g2[1][jp] - g1[1][jp] * g2[0][jp];
        }
    };

    auto mfma2 = [&](A2U (&a2u)[3], const v8h& b2lo, const v8h& b2hi) {
#pragma unroll
        for (int vc = 0; vc < 3; ++vc) {
            coacc[vc][0] = __builtin_amdgcn_mfma_f32_16x16x32_f16(a2u[vc].v, b2lo, coacc[vc][0], 0, 0, 0);
            coacc[vc][1] = __builtin_amdgcn_mfma_f32_16x16x32_f16(a2u[vc].v, b2hi, coacc[vc][1], 0, 0, 0);
        }
    };

    // ---- main loop: gb = q, q+2 (NGB = 3)
    if constexpr (USE_WS) {
        const v8h* base_a = (const v8h*)A1buf + lane;
        const v8h* base_b = (const v8h*)B2buf + lane;
        for (int gb = q; gb < NGB; gb += 2) {
            const int off = gb * 128;
            const v8h Aa = base_a[off], Ab = base_a[off + 64];
            const v8h Ba = base_b[off], Bb = base_b[off + 64];
            A2U a2u[3];
            v4f ag[2][3];
            mfma1h(Aa, ag);
            crossh(ag, a2u, 0);
            mfma1h(Ab, ag);
            crossh(ag, a2u, 1);
            mfma2(a2u, Ba, Bb);
        }
    } else {
        for (int gb = q; gb < NGB; gb += 2) {
            v8h Aa, Ab, Ba, Bb;
#pragma unroll
            for (int j = 0; j < 8; ++j) {
                const int k = (j < 4) ? (lhi * 4 + j) : (16 + lhi * 4 + (j - 4));
                Aa[j] = (f16)Yat(k, gb * 32 + llo, false);
                Ab[j] = (f16)Yat(k, gb * 32 + 16 + llo, false);
                const int gg = gb * 32 + ((j < 4) ? (lhi * 4 + j) : (16 + lhi * 4 + (j - 4)));
                Ba[j] = (f16)Yat(llo, gg, true);
                Bb[j] = (f16)Yat(16 + llo, gg, true);
            }
            A2U a2u[3];
            v4f ag[2][3];
            mfma1h(Aa, ag);
            crossh(ag, a2u, 0);
            mfma1h(Ab, ag);
            crossh(ag, a2u, 1);
            mfma2(a2u, Ba, Bb);
        }
    }

    // ---- CO: parallel write — q=0 -> cob, q=1 -> cob2 (no serialized stages).
    // Sync first: cob aliases hb (hoist reads done), cob2 aliases xsl (dead).
    __syncthreads();
    {
        float* cdst = q ? cob2 : cob;
#pragma unroll
        for (int vc = 0; vc < 3; ++vc)
#pragma unroll
            for (int t = 0; t < 2; ++t)
#pragma unroll
                for (int j = 0; j < 4; ++j) {
                    const int row = (2 * vc + h) * 16 + lhi * 4 + j;
                    cdst[row * CSTR + t * 16 + llo] = coacc[vc][t][j];
                }
    }
    __syncthreads();

    // ---- epilogue (MFMA): wave v=wid<3: out = W_l^T x (cob + cob2)
    if (wid < 3) {
        const int v = wid;
        const float* Wop = Wouts + p * 5120;
        float* outp = out + (n * 96 + p * 32) * 75 + v * 25;
        const int k0s[5] = {0, 1, 4, 9, 16};
        const int kws[5] = {1, 3, 5, 7, 9};
#pragma unroll
        for (int l = 0; l < 5; ++l) {
            const int k0 = k0s[l], kw = kws[l];
            v8h Bf;
            const int kk = (llo < kw) ? (k0 + llo) : k0;
#pragma unroll
            for (int j = 0; j < 8; ++j) {
                const int a = (j < 4) ? (lhi * 4 + j) : (16 + lhi * 4 + (j - 4));
                const int ci = (v * 32 + a) * CSTR + kk;
                const float bv = (llo < kw) ? (cob[ci] + cob2[ci]) : 0.0f;
                Bf[j] = (f16)bv;
            }
#pragma unroll
            for (int bt = 0; bt < 2; ++bt) {
                v8h Af;
#pragma unroll
                for (int j = 0; j < 8; ++j) {
                    const int a = (j < 4) ? (lhi * 4 + j) : (16 + lhi * 4 + (j - 4));
                    Af[j] = (f16)Wop[l * 1024 + a * 32 + bt * 16 + llo];
                }
                v4f D = __builtin_amdgcn_mfma_f32_16x16x32_f16(Af, Bf, zero4, 0, 0, 0);
                if (llo < kw) {
#pragma unroll
                    for (int jj = 0; jj < 4; ++jj)
                        outp[(bt * 16 + lhi * 4 + jj) * 75 + k0 + llo] = D[jj];
                }
            }
        }
    }
}

extern "C" void kernel_launch(void* const* d_in, const int* in_sizes, int n_in,
                              void* d_out, int out_size, void* d_ws, size_t ws_size,
                              hipStream_t stream) {
    const float* x1 = (const float*)d_in[0];
    const float* x2 = (const float*)d_in[1];
    const float* W1s = (const float*)d_in[2];
    const float* W2s = (const float*)d_in[3];
    const float* Wouts = (const float*)d_in[4];
    float* out = (float*)d_out;

    f16* A1buf = (f16*)d_ws;                       // 3072 f16 = 6 KB
    f16* B2buf = (f16*)((char*)d_ws + 8192);       // 6 KB

    if (ws_size >= 16384) {
        vg_prep<<<24, 256, 0, stream>>>(A1buf, B2buf);
        vg_main<true><<<1536, 256, 0, stream>>>(x1, x2, W1s, W2s, Wouts,
                                                A1buf, B2buf, out);
    } else {
        vg_main<false><<<1536, 256, 0, stream>>>(x1, x2, W1s, W2s, Wouts,
                                                 nullptr, nullptr, out);
    }
}